// Round 1
// baseline (1489.798 us; speedup 1.0000x reference)
//
#include <hip/hip_runtime.h>

// Problem constants (from reference)
#define NVN 65536
#define NCN 32768
#define NB 4
#define DIM 32
#define NE 262144
#define HID 40
#define MSGD 20

// ---------------- CSR build ----------------

__global__ __launch_bounds__(256) void hist_kernel(const int* __restrict__ to_ind,
                                                   int* __restrict__ counts) {
    int e = blockIdx.x * 256 + threadIdx.x;
    atomicAdd(&counts[to_ind[e]], 1);
}

__global__ __launch_bounds__(1024) void scan_kernel(const int* __restrict__ counts,
                                                    int* __restrict__ start,
                                                    int* __restrict__ cursor) {
    __shared__ int sd[1024];
    int t = threadIdx.x;
    int base = t * 32;
    int local[32];
    int s = 0;
#pragma unroll
    for (int i = 0; i < 32; i++) { local[i] = counts[base + i]; s += local[i]; }
    sd[t] = s;
    __syncthreads();
    for (int off = 1; off < 1024; off <<= 1) {
        int v = (t >= off) ? sd[t - off] : 0;
        __syncthreads();
        sd[t] += v;
        __syncthreads();
    }
    int run = sd[t] - s;  // exclusive prefix of this thread's chunk
#pragma unroll
    for (int i = 0; i < 32; i++) {
        start[base + i] = run;
        cursor[base + i] = run;
        run += local[i];
    }
    if (t == 1023) start[NCN] = run;  // total = NE
}

// scatter: edge_from[csr_pos] = from_ind[e]   (we never need the edge id itself)
__global__ __launch_bounds__(256) void scatter_kernel(const int* __restrict__ to_ind,
                                                      const int* __restrict__ from_ind,
                                                      int* __restrict__ cursor,
                                                      int* __restrict__ edge_from) {
    int e = blockIdx.x * 256 + threadIdx.x;
    int c = to_ind[e];
    int pos = atomicAdd(&cursor[c], 1);
    edge_from[pos] = from_ind[e];
}

// ---------------- Precompute U = h_from @ Wm1[0:32]  -> [B*NVN, 40] ----------------

__global__ __launch_bounds__(256) void precompU_kernel(const float* __restrict__ h_from,
                                                       const float* __restrict__ Wm1,
                                                       float* __restrict__ U) {
    __shared__ float w[DIM * HID];
    int tid = threadIdx.x;
    for (int i = tid; i < DIM * HID; i += 256) w[i] = Wm1[i];
    __syncthreads();
    size_t row = (size_t)blockIdx.x * 256 + tid;  // b*NVN + v
    const float4* hf4 = (const float4*)(h_from + row * DIM);
    float acc[HID];
#pragma unroll
    for (int h = 0; h < HID; h++) acc[h] = 0.f;
#pragma unroll
    for (int q = 0; q < DIM / 4; q++) {
        float4 x = hf4[q];
#pragma unroll
        for (int h = 0; h < HID; h++) {
            acc[h] += x.x * w[(4 * q + 0) * HID + h];
            acc[h] += x.y * w[(4 * q + 1) * HID + h];
            acc[h] += x.z * w[(4 * q + 2) * HID + h];
            acc[h] += x.w * w[(4 * q + 3) * HID + h];
        }
    }
    float4* Ur = (float4*)(U + row * HID);
#pragma unroll
    for (int q = 0; q < HID / 4; q++)
        Ur[q] = make_float4(acc[4 * q], acc[4 * q + 1], acc[4 * q + 2], acc[4 * q + 3]);
}

// ------- Precompute T = h_to @ Wm1[32:64],  P = h_to @ We1[20:52] + logit*We1[52] -------

__global__ __launch_bounds__(256) void precompTP_kernel(const float* __restrict__ h_to,
                                                        const float* __restrict__ logit,
                                                        const float* __restrict__ Wm1,
                                                        const float* __restrict__ We1,
                                                        float* __restrict__ T,
                                                        float* __restrict__ P) {
    __shared__ float wm1b[DIM * HID];
    __shared__ float we1b[DIM * HID];
    __shared__ float we1l[HID];
    int tid = threadIdx.x;
    for (int i = tid; i < DIM * HID; i += 256) {
        wm1b[i] = Wm1[DIM * HID + i];          // rows 32..63
        we1b[i] = We1[MSGD * HID + i];         // rows 20..51
    }
    if (tid < HID) we1l[tid] = We1[(MSGD + DIM) * HID + tid];  // row 52
    __syncthreads();
    size_t row = (size_t)blockIdx.x * 256 + tid;  // b*NCN + c
    const float4* ht4 = (const float4*)(h_to + row * DIM);
    float lg = logit[row];
    float aT[HID], aP[HID];
#pragma unroll
    for (int h = 0; h < HID; h++) { aT[h] = 0.f; aP[h] = lg * we1l[h]; }
#pragma unroll
    for (int q = 0; q < DIM / 4; q++) {
        float4 x = ht4[q];
#pragma unroll
        for (int h = 0; h < HID; h++) {
            aT[h] += x.x * wm1b[(4 * q + 0) * HID + h];
            aT[h] += x.y * wm1b[(4 * q + 1) * HID + h];
            aT[h] += x.z * wm1b[(4 * q + 2) * HID + h];
            aT[h] += x.w * wm1b[(4 * q + 3) * HID + h];
            aP[h] += x.x * we1b[(4 * q + 0) * HID + h];
            aP[h] += x.y * we1b[(4 * q + 1) * HID + h];
            aP[h] += x.z * we1b[(4 * q + 2) * HID + h];
            aP[h] += x.w * we1b[(4 * q + 3) * HID + h];
        }
    }
    float4* Tr = (float4*)(T + row * HID);
    float4* Pr = (float4*)(P + row * HID);
#pragma unroll
    for (int q = 0; q < HID / 4; q++) {
        Tr[q] = make_float4(aT[4 * q], aT[4 * q + 1], aT[4 * q + 2], aT[4 * q + 3]);
        Pr[q] = make_float4(aP[4 * q], aP[4 * q + 1], aP[4 * q + 2], aP[4 * q + 3]);
    }
}

// ---------------- Fused aggregate + embed MLP: one thread per (b, c) ----------------

__global__ __launch_bounds__(256) void agg_kernel(const float* __restrict__ U,
                                                  const float* __restrict__ T,
                                                  const float* __restrict__ P,
                                                  const int* __restrict__ start,
                                                  const int* __restrict__ edge_from,
                                                  const float* __restrict__ Wm2,
                                                  const float* __restrict__ We1,
                                                  const float* __restrict__ We2,
                                                  float* __restrict__ out) {
    __shared__ float wm2[HID * MSGD];   // [40][20]
    __shared__ float we1a[MSGD * HID];  // rows 0..19 of We1: [20][40]
    __shared__ float we2[HID * DIM];    // [40][32]
    int tid = threadIdx.x;
    for (int i = tid; i < HID * MSGD; i += 256) { wm2[i] = Wm2[i]; we1a[i] = We1[i]; }
    for (int i = tid; i < HID * DIM; i += 256) we2[i] = We2[i];
    __syncthreads();

    int gid = blockIdx.x * 256 + tid;   // b*NCN + c
    int c = gid & (NCN - 1);
    int b = gid >> 15;

    float tv[HID];
    {
        const float4* T4 = (const float4*)(T + (size_t)gid * HID);
#pragma unroll
        for (int q = 0; q < HID / 4; q++) {
            float4 v = T4[q];
            tv[4 * q + 0] = v.x; tv[4 * q + 1] = v.y;
            tv[4 * q + 2] = v.z; tv[4 * q + 3] = v.w;
        }
    }
    float m[MSGD];
#pragma unroll
    for (int k = 0; k < MSGD; k++) m[k] = 0.f;

    int s0 = start[c], s1 = start[c + 1];
    const float* Ub = U + (size_t)b * NVN * HID;
    for (int idx = s0; idx < s1; ++idx) {
        int v = edge_from[idx];
        const float4* U4 = (const float4*)(Ub + (size_t)v * HID);
#pragma unroll
        for (int q = 0; q < HID / 4; q++) {
            float4 u = U4[q];
            float h0 = fmaxf(u.x + tv[4 * q + 0], 0.f);
            float h1 = fmaxf(u.y + tv[4 * q + 1], 0.f);
            float h2 = fmaxf(u.z + tv[4 * q + 2], 0.f);
            float h3 = fmaxf(u.w + tv[4 * q + 3], 0.f);
#pragma unroll
            for (int k = 0; k < MSGD; k++) {
                m[k] += h0 * wm2[(4 * q + 0) * MSGD + k];
                m[k] += h1 * wm2[(4 * q + 1) * MSGD + k];
                m[k] += h2 * wm2[(4 * q + 2) * MSGD + k];
                m[k] += h3 * wm2[(4 * q + 3) * MSGD + k];
            }
        }
    }

    // embed MLP: out = relu(m @ We1a + P) @ We2
    float o[DIM];
#pragma unroll
    for (int d = 0; d < DIM; d++) o[d] = 0.f;
    const float4* P4 = (const float4*)(P + (size_t)gid * HID);
#pragma unroll
    for (int q = 0; q < HID / 4; q++) {
        float4 pv = P4[q];
        float pw[4] = {pv.x, pv.y, pv.z, pv.w};
#pragma unroll
        for (int r = 0; r < 4; r++) {
            int h = 4 * q + r;
            float a = pw[r];
#pragma unroll
            for (int k = 0; k < MSGD; k++) a += m[k] * we1a[k * HID + h];
            a = fmaxf(a, 0.f);
#pragma unroll
            for (int d = 0; d < DIM; d++) o[d] += a * we2[h * DIM + d];
        }
    }
    float4* O4 = (float4*)(out + (size_t)gid * DIM);
#pragma unroll
    for (int q = 0; q < DIM / 4; q++)
        O4[q] = make_float4(o[4 * q], o[4 * q + 1], o[4 * q + 2], o[4 * q + 3]);
}

// ---------------- host ----------------

extern "C" void kernel_launch(void* const* d_in, const int* in_sizes, int n_in,
                              void* d_out, int out_size, void* d_ws, size_t ws_size,
                              hipStream_t stream) {
    const float* h_from   = (const float*)d_in[0];
    const float* h_to_x   = (const float*)d_in[1];
    const float* h_to_z   = (const float*)d_in[2];
    const float* hx_logit = (const float*)d_in[3];
    const float* hz_logit = (const float*)d_in[4];
    const int*   from_x   = (const int*)d_in[5];
    const int*   to_x     = (const int*)d_in[6];
    const int*   from_z   = (const int*)d_in[7];
    const int*   to_z     = (const int*)d_in[8];
    const float* Wm1_x    = (const float*)d_in[9];
    const float* Wm2_x    = (const float*)d_in[10];
    const float* Wm1_z    = (const float*)d_in[11];
    const float* Wm2_z    = (const float*)d_in[12];
    const float* We1_x    = (const float*)d_in[13];
    const float* We2_x    = (const float*)d_in[14];
    const float* We1_z    = (const float*)d_in[15];
    const float* We2_z    = (const float*)d_in[16];

    // Workspace layout (bytes), total = 85,328,128 (~81.4 MiB)
    char* ws = (char*)d_ws;
    float* U         = (float*)(ws + 0);          // 4*65536*40*4 = 41,943,040
    float* T         = (float*)(ws + 41943040);   // 4*32768*40*4 = 20,971,520
    float* P         = (float*)(ws + 62914560);   // 20,971,520
    int*   start     = (int*)(ws + 83886080);     // (32768+1)*4
    int*   cursor    = (int*)(ws + 84017408);     // 32768*4
    int*   counts    = (int*)(ws + 84148480);     // 32768*4
    int*   edge_from = (int*)(ws + 84279552);     // 262144*4
    float* out = (float*)d_out;

    for (int side = 0; side < 2; side++) {
        const float* h_to   = side ? h_to_z   : h_to_x;
        const float* logit  = side ? hz_logit : hx_logit;
        const int*   f_ind  = side ? from_z   : from_x;
        const int*   t_ind  = side ? to_z     : to_x;
        const float* Wm1    = side ? Wm1_z    : Wm1_x;
        const float* Wm2    = side ? Wm2_z    : Wm2_x;
        const float* We1    = side ? We1_z    : We1_x;
        const float* We2    = side ? We2_z    : We2_x;
        float* out_s = out + (size_t)side * NB * NCN * DIM;

        hipMemsetAsync(counts, 0, NCN * sizeof(int), stream);
        hist_kernel<<<NE / 256, 256, 0, stream>>>(t_ind, counts);
        scan_kernel<<<1, 1024, 0, stream>>>(counts, start, cursor);
        scatter_kernel<<<NE / 256, 256, 0, stream>>>(t_ind, f_ind, cursor, edge_from);
        precompU_kernel<<<NB * NVN / 256, 256, 0, stream>>>(h_from, Wm1, U);
        precompTP_kernel<<<NB * NCN / 256, 256, 0, stream>>>(h_to, logit, Wm1, We1, T, P);
        agg_kernel<<<NB * NCN / 256, 256, 0, stream>>>(U, T, P, start, edge_from,
                                                       Wm2, We1, We2, out_s);
    }
}

// Round 2
// 428.555 us; speedup vs baseline: 3.4763x; 3.4763x over previous
//
#include <hip/hip_runtime.h>

// Problem constants (from reference)
#define NVN 65536
#define NCN 32768
#define NB 4
#define DIM 32
#define NE 262144
#define HID 40
#define MSGD 20

__device__ __forceinline__ void fma4(float4& acc, float a, const float4 w) {
    acc.x += a * w.x; acc.y += a * w.y; acc.z += a * w.z; acc.w += a * w.w;
}

// ---------------- CSR build ----------------

__global__ __launch_bounds__(256) void hist_kernel(const int* __restrict__ to_ind,
                                                   int* __restrict__ counts) {
    int e = blockIdx.x * 256 + threadIdx.x;
    atomicAdd(&counts[to_ind[e]], 1);
}

__global__ __launch_bounds__(1024) void scan_kernel(const int* __restrict__ counts,
                                                    int* __restrict__ start,
                                                    int* __restrict__ cursor) {
    __shared__ int sd[1024];
    int t = threadIdx.x;
    int base = t * 32;
    int local[32];
    int s = 0;
#pragma unroll
    for (int i = 0; i < 32; i++) { local[i] = counts[base + i]; s += local[i]; }
    sd[t] = s;
    __syncthreads();
    for (int off = 1; off < 1024; off <<= 1) {
        int v = (t >= off) ? sd[t - off] : 0;
        __syncthreads();
        sd[t] += v;
        __syncthreads();
    }
    int run = sd[t] - s;  // exclusive prefix of this thread's chunk
#pragma unroll
    for (int i = 0; i < 32; i++) {
        start[base + i] = run;
        cursor[base + i] = run;
        run += local[i];
    }
    if (t == 1023) start[NCN] = run;  // total = NE
}

__global__ __launch_bounds__(256) void scatter_kernel(const int* __restrict__ to_ind,
                                                      const int* __restrict__ from_ind,
                                                      int* __restrict__ cursor,
                                                      int* __restrict__ edge_from) {
    int e = blockIdx.x * 256 + threadIdx.x;
    int c = to_ind[e];
    int pos = atomicAdd(&cursor[c], 1);
    edge_from[pos] = from_ind[e];
}

// ---------------- Precompute U = h_from @ Wm1[0:32]  -> [B*NVN, 40] ----------------

__global__ __launch_bounds__(256) void precompU_kernel(const float* __restrict__ h_from,
                                                       const float* __restrict__ Wm1,
                                                       float* __restrict__ U) {
    __shared__ float w[DIM * HID];
    int tid = threadIdx.x;
    for (int i = tid; i < DIM * HID; i += 256) w[i] = Wm1[i];
    __syncthreads();
    size_t row = (size_t)blockIdx.x * 256 + tid;  // b*NVN + v
    const float4* hf4 = (const float4*)(h_from + row * DIM);
    float acc[HID];
#pragma unroll
    for (int h = 0; h < HID; h++) acc[h] = 0.f;
#pragma unroll
    for (int q = 0; q < DIM / 4; q++) {
        float4 x = hf4[q];
#pragma unroll
        for (int h = 0; h < HID; h++) {
            acc[h] += x.x * w[(4 * q + 0) * HID + h];
            acc[h] += x.y * w[(4 * q + 1) * HID + h];
            acc[h] += x.z * w[(4 * q + 2) * HID + h];
            acc[h] += x.w * w[(4 * q + 3) * HID + h];
        }
    }
    float4* Ur = (float4*)(U + row * HID);
#pragma unroll
    for (int q = 0; q < HID / 4; q++)
        Ur[q] = make_float4(acc[4 * q], acc[4 * q + 1], acc[4 * q + 2], acc[4 * q + 3]);
}

// ------- Precompute T = h_to @ Wm1[32:64],  P = h_to @ We1[20:52] + logit*We1[52] -------

__global__ __launch_bounds__(256) void precompTP_kernel(const float* __restrict__ h_to,
                                                        const float* __restrict__ logit,
                                                        const float* __restrict__ Wm1,
                                                        const float* __restrict__ We1,
                                                        float* __restrict__ T,
                                                        float* __restrict__ P) {
    __shared__ float wm1b[DIM * HID];
    __shared__ float we1b[DIM * HID];
    __shared__ float we1l[HID];
    int tid = threadIdx.x;
    for (int i = tid; i < DIM * HID; i += 256) {
        wm1b[i] = Wm1[DIM * HID + i];          // rows 32..63
        we1b[i] = We1[MSGD * HID + i];         // rows 20..51
    }
    if (tid < HID) we1l[tid] = We1[(MSGD + DIM) * HID + tid];  // row 52
    __syncthreads();
    size_t row = (size_t)blockIdx.x * 256 + tid;  // b*NCN + c
    const float4* ht4 = (const float4*)(h_to + row * DIM);
    float lg = logit[row];
    float aT[HID], aP[HID];
#pragma unroll
    for (int h = 0; h < HID; h++) { aT[h] = 0.f; aP[h] = lg * we1l[h]; }
#pragma unroll
    for (int q = 0; q < DIM / 4; q++) {
        float4 x = ht4[q];
#pragma unroll
        for (int h = 0; h < HID; h++) {
            aT[h] += x.x * wm1b[(4 * q + 0) * HID + h];
            aT[h] += x.y * wm1b[(4 * q + 1) * HID + h];
            aT[h] += x.z * wm1b[(4 * q + 2) * HID + h];
            aT[h] += x.w * wm1b[(4 * q + 3) * HID + h];
            aP[h] += x.x * we1b[(4 * q + 0) * HID + h];
            aP[h] += x.y * we1b[(4 * q + 1) * HID + h];
            aP[h] += x.z * we1b[(4 * q + 2) * HID + h];
            aP[h] += x.w * we1b[(4 * q + 3) * HID + h];
        }
    }
    float4* Tr = (float4*)(T + row * HID);
    float4* Pr = (float4*)(P + row * HID);
#pragma unroll
    for (int q = 0; q < HID / 4; q++) {
        Tr[q] = make_float4(aT[4 * q], aT[4 * q + 1], aT[4 * q + 2], aT[4 * q + 3]);
        Pr[q] = make_float4(aP[4 * q], aP[4 * q + 1], aP[4 * q + 2], aP[4 * q + 3]);
    }
}

// ------- Fused aggregate + embed MLP: FOUR lanes per (b, c) node -------
// Lane r of a 4-lane group owns h-chunks (float4 indices): {r, 4+r} and (r<2: {8+r}).
// Key algebra: sum relu activations over edges FIRST, then one 40x20 matvec per node.

__global__ __launch_bounds__(256) void agg_kernel(const float* __restrict__ U,
                                                  const float* __restrict__ T,
                                                  const float* __restrict__ P,
                                                  const int* __restrict__ start,
                                                  const int* __restrict__ edge_from,
                                                  const float* __restrict__ Wm2,
                                                  const float* __restrict__ We1,
                                                  const float* __restrict__ We2,
                                                  float* __restrict__ out) {
    __shared__ __attribute__((aligned(16))) float wm2s[HID * MSGD];   // [40][20]
    __shared__ __attribute__((aligned(16))) float we1s[MSGD * HID];   // [20][40]
    __shared__ __attribute__((aligned(16))) float we2s[HID * DIM];    // [40][32]
    int tid = threadIdx.x;
    for (int i = tid; i < HID * MSGD; i += 256) { wm2s[i] = Wm2[i]; we1s[i] = We1[i]; }
    for (int i = tid; i < HID * DIM; i += 256) we2s[i] = We2[i];
    __syncthreads();

    int gt = blockIdx.x * 256 + tid;
    int grp = gt >> 2;            // node id: b*NCN + c
    int r = gt & 3;               // lane within group
    int c = grp & (NCN - 1);
    int b = grp >> 15;

    // T chunks for this lane
    const float4* T4 = (const float4*)(T + (size_t)grp * HID);
    float4 t0 = T4[r];
    float4 t1 = T4[4 + r];
    float4 t2 = make_float4(0.f, 0.f, 0.f, 0.f);
    if (r < 2) t2 = T4[8 + r];

    // ---- edge loop: accumulate s = sum_e relu(u_e + t) over this node's edges ----
    float4 sA = make_float4(0.f, 0.f, 0.f, 0.f);
    float4 sB = make_float4(0.f, 0.f, 0.f, 0.f);
    float4 sC = make_float4(0.f, 0.f, 0.f, 0.f);
    int e0 = start[c], e1 = start[c + 1];
    const float* Ub = U + (size_t)b * NVN * HID;
    for (int idx = e0; idx < e1; ++idx) {
        int v = edge_from[idx];
        const float4* U4 = (const float4*)(Ub + (size_t)v * HID);
        float4 uA = U4[r];
        float4 uB = U4[4 + r];
        sA.x += fmaxf(uA.x + t0.x, 0.f); sA.y += fmaxf(uA.y + t0.y, 0.f);
        sA.z += fmaxf(uA.z + t0.z, 0.f); sA.w += fmaxf(uA.w + t0.w, 0.f);
        sB.x += fmaxf(uB.x + t1.x, 0.f); sB.y += fmaxf(uB.y + t1.y, 0.f);
        sB.z += fmaxf(uB.z + t1.z, 0.f); sB.w += fmaxf(uB.w + t1.w, 0.f);
        if (r < 2) {
            float4 uC = U4[8 + r];
            sC.x += fmaxf(uC.x + t2.x, 0.f); sC.y += fmaxf(uC.y + t2.y, 0.f);
            sC.z += fmaxf(uC.z + t2.z, 0.f); sC.w += fmaxf(uC.w + t2.w, 0.f);
        }
    }

    // ---- m = s @ Wm2 : per-lane partial over this lane's h's ----
    float4 m4[5];
#pragma unroll
    for (int kq = 0; kq < 5; kq++) m4[kq] = make_float4(0.f, 0.f, 0.f, 0.f);

#define MROW(av, h) { const float4* w4_ = (const float4*)(wm2s + (h) * MSGD); \
    fma4(m4[0], (av), w4_[0]); fma4(m4[1], (av), w4_[1]); fma4(m4[2], (av), w4_[2]); \
    fma4(m4[3], (av), w4_[3]); fma4(m4[4], (av), w4_[4]); }

    MROW(sA.x, 4 * r + 0); MROW(sA.y, 4 * r + 1); MROW(sA.z, 4 * r + 2); MROW(sA.w, 4 * r + 3);
    MROW(sB.x, 16 + 4 * r + 0); MROW(sB.y, 16 + 4 * r + 1);
    MROW(sB.z, 16 + 4 * r + 2); MROW(sB.w, 16 + 4 * r + 3);
    if (r < 2) {
        MROW(sC.x, 32 + 4 * r + 0); MROW(sC.y, 32 + 4 * r + 1);
        MROW(sC.z, 32 + 4 * r + 2); MROW(sC.w, 32 + 4 * r + 3);
    }
#undef MROW

    float mm[MSGD];
#pragma unroll
    for (int kq = 0; kq < 5; kq++) {
        mm[4 * kq + 0] = m4[kq].x; mm[4 * kq + 1] = m4[kq].y;
        mm[4 * kq + 2] = m4[kq].z; mm[4 * kq + 3] = m4[kq].w;
    }
    // reduce partial m across the 4 lanes of the group (each lane ends with full m)
#pragma unroll
    for (int k = 0; k < MSGD; k++) mm[k] += __shfl_xor(mm[k], 1);
#pragma unroll
    for (int k = 0; k < MSGD; k++) mm[k] += __shfl_xor(mm[k], 2);

    // ---- a = relu(m @ We1[0:20] + P) for this lane's h's ----
    const float4* P4 = (const float4*)(P + (size_t)grp * HID);
    float4 aA = P4[r];
    float4 aB = P4[4 + r];
    float4 aC = make_float4(0.f, 0.f, 0.f, 0.f);
    if (r < 2) aC = P4[8 + r];
#pragma unroll
    for (int k = 0; k < MSGD; k++) {
        float mk = mm[k];
        const float4* w4 = (const float4*)(we1s + k * HID);
        fma4(aA, mk, w4[r]);
        fma4(aB, mk, w4[4 + r]);
        if (r < 2) fma4(aC, mk, w4[8 + r]);
    }
    aA.x = fmaxf(aA.x, 0.f); aA.y = fmaxf(aA.y, 0.f); aA.z = fmaxf(aA.z, 0.f); aA.w = fmaxf(aA.w, 0.f);
    aB.x = fmaxf(aB.x, 0.f); aB.y = fmaxf(aB.y, 0.f); aB.z = fmaxf(aB.z, 0.f); aB.w = fmaxf(aB.w, 0.f);
    aC.x = fmaxf(aC.x, 0.f); aC.y = fmaxf(aC.y, 0.f); aC.z = fmaxf(aC.z, 0.f); aC.w = fmaxf(aC.w, 0.f);

    // ---- o = a @ We2 : per-lane partial over this lane's h's ----
    float4 o4[8];
#pragma unroll
    for (int dq = 0; dq < 8; dq++) o4[dq] = make_float4(0.f, 0.f, 0.f, 0.f);

#define OROW(av, h) { const float4* w4_ = (const float4*)(we2s + (h) * DIM); \
    fma4(o4[0], (av), w4_[0]); fma4(o4[1], (av), w4_[1]); fma4(o4[2], (av), w4_[2]); \
    fma4(o4[3], (av), w4_[3]); fma4(o4[4], (av), w4_[4]); fma4(o4[5], (av), w4_[5]); \
    fma4(o4[6], (av), w4_[6]); fma4(o4[7], (av), w4_[7]); }

    OROW(aA.x, 4 * r + 0); OROW(aA.y, 4 * r + 1); OROW(aA.z, 4 * r + 2); OROW(aA.w, 4 * r + 3);
    OROW(aB.x, 16 + 4 * r + 0); OROW(aB.y, 16 + 4 * r + 1);
    OROW(aB.z, 16 + 4 * r + 2); OROW(aB.w, 16 + 4 * r + 3);
    if (r < 2) {
        OROW(aC.x, 32 + 4 * r + 0); OROW(aC.y, 32 + 4 * r + 1);
        OROW(aC.z, 32 + 4 * r + 2); OROW(aC.w, 32 + 4 * r + 3);
    }
#undef OROW

    float oo[DIM];
#pragma unroll
    for (int dq = 0; dq < 8; dq++) {
        oo[4 * dq + 0] = o4[dq].x; oo[4 * dq + 1] = o4[dq].y;
        oo[4 * dq + 2] = o4[dq].z; oo[4 * dq + 3] = o4[dq].w;
    }
#pragma unroll
    for (int d = 0; d < DIM; d++) oo[d] += __shfl_xor(oo[d], 1);
#pragma unroll
    for (int d = 0; d < DIM; d++) oo[d] += __shfl_xor(oo[d], 2);

    float4* Orow = (float4*)(out + (size_t)grp * DIM);
    switch (r) {
        case 0:
            Orow[0] = make_float4(oo[0], oo[1], oo[2], oo[3]);
            Orow[1] = make_float4(oo[4], oo[5], oo[6], oo[7]);
            break;
        case 1:
            Orow[2] = make_float4(oo[8], oo[9], oo[10], oo[11]);
            Orow[3] = make_float4(oo[12], oo[13], oo[14], oo[15]);
            break;
        case 2:
            Orow[4] = make_float4(oo[16], oo[17], oo[18], oo[19]);
            Orow[5] = make_float4(oo[20], oo[21], oo[22], oo[23]);
            break;
        default:
            Orow[6] = make_float4(oo[24], oo[25], oo[26], oo[27]);
            Orow[7] = make_float4(oo[28], oo[29], oo[30], oo[31]);
            break;
    }
}

// ---------------- host ----------------

extern "C" void kernel_launch(void* const* d_in, const int* in_sizes, int n_in,
                              void* d_out, int out_size, void* d_ws, size_t ws_size,
                              hipStream_t stream) {
    const float* h_from   = (const float*)d_in[0];
    const float* h_to_x   = (const float*)d_in[1];
    const float* h_to_z   = (const float*)d_in[2];
    const float* hx_logit = (const float*)d_in[3];
    const float* hz_logit = (const float*)d_in[4];
    const int*   from_x   = (const int*)d_in[5];
    const int*   to_x     = (const int*)d_in[6];
    const int*   from_z   = (const int*)d_in[7];
    const int*   to_z     = (const int*)d_in[8];
    const float* Wm1_x    = (const float*)d_in[9];
    const float* Wm2_x    = (const float*)d_in[10];
    const float* Wm1_z    = (const float*)d_in[11];
    const float* Wm2_z    = (const float*)d_in[12];
    const float* We1_x    = (const float*)d_in[13];
    const float* We2_x    = (const float*)d_in[14];
    const float* We1_z    = (const float*)d_in[15];
    const float* We2_z    = (const float*)d_in[16];

    // Workspace layout (bytes), total = 85,328,128 (~81.4 MiB)
    char* ws = (char*)d_ws;
    float* U         = (float*)(ws + 0);          // 4*65536*40*4 = 41,943,040
    float* T         = (float*)(ws + 41943040);   // 4*32768*40*4 = 20,971,520
    float* P         = (float*)(ws + 62914560);   // 20,971,520
    int*   start     = (int*)(ws + 83886080);     // (32768+1)*4
    int*   cursor    = (int*)(ws + 84017408);     // 32768*4
    int*   counts    = (int*)(ws + 84148480);     // 32768*4
    int*   edge_from = (int*)(ws + 84279552);     // 262144*4
    float* out = (float*)d_out;

    for (int side = 0; side < 2; side++) {
        const float* h_to   = side ? h_to_z   : h_to_x;
        const float* logit  = side ? hz_logit : hx_logit;
        const int*   f_ind  = side ? from_z   : from_x;
        const int*   t_ind  = side ? to_z     : to_x;
        const float* Wm1    = side ? Wm1_z    : Wm1_x;
        const float* Wm2    = side ? Wm2_z    : Wm2_x;
        const float* We1    = side ? We1_z    : We1_x;
        const float* We2    = side ? We2_z    : We2_x;
        float* out_s = out + (size_t)side * NB * NCN * DIM;

        hipMemsetAsync(counts, 0, NCN * sizeof(int), stream);
        hist_kernel<<<NE / 256, 256, 0, stream>>>(t_ind, counts);
        scan_kernel<<<1, 1024, 0, stream>>>(counts, start, cursor);
        scatter_kernel<<<NE / 256, 256, 0, stream>>>(t_ind, f_ind, cursor, edge_from);
        precompU_kernel<<<NB * NVN / 256, 256, 0, stream>>>(h_from, Wm1, U);
        precompTP_kernel<<<NB * NCN / 256, 256, 0, stream>>>(h_to, logit, Wm1, We1, T, P);
        agg_kernel<<<NB * NCN * 4 / 256, 256, 0, stream>>>(U, T, P, start, edge_from,
                                                           Wm2, We1, We2, out_s);
    }
}